// Round 2
// baseline (679.912 us; speedup 1.0000x reference)
//
#include <hip/hip_runtime.h>
#include <math.h>

typedef __bf16 bf16_t;
typedef __bf16 bf16x8 __attribute__((ext_vector_type(8)));
typedef float  f32x4  __attribute__((ext_vector_type(4)));

__device__ __forceinline__ void gl2lds16(const void* g, void* l) {
  __builtin_amdgcn_global_load_lds((__attribute__((address_space(1))) void*)g,
                                   (__attribute__((address_space(3))) void*)l,
                                   16, 0, 0);
}

// ---------------------------------------------------------------------------
// bf16 GEMM, C = A * B^T  (A: [M][K], B: [N][K], both K-contiguous bf16)
// MODE 0: out0 bf16 = sigmoid(v)            (q)
// MODE 1: out0 bf16 = sigmoid(-v) (=1-f=k), out1 f32 = logsigmoid(v) (=g)
// MODE 2: out0 bf16 = v                     (values)
// MODE 3: out0 f32  = v                     (final output)
// ---------------------------------------------------------------------------
template<int MODE>
__global__ __launch_bounds__(256, 2)
void gemm_bt(const bf16_t* __restrict__ A, const bf16_t* __restrict__ B,
             void* __restrict__ out0, float* __restrict__ out1,
             int M, int N, int K)
{
  __shared__ __align__(16) bf16_t As[128 * 32];
  __shared__ __align__(16) bf16_t Bs[128 * 32];
  const int tt   = threadIdx.x;
  const int wave = tt >> 6;
  const int lane = tt & 63;
  const int nblk = N >> 7;
  const int m0 = (int)(blockIdx.x / nblk) * 128;
  const int n0 = (int)(blockIdx.x % nblk) * 128;
  const int wr = (wave >> 1) * 64;
  const int wc = (wave & 1) * 64;
  const int r  = lane & 15;
  const int ko = (lane >> 4) * 8;
  const int c0 = tt, c1 = tt + 256;
  const int ar0 = c0 >> 2, ac0 = (c0 & 3) * 8;
  const int ar1 = c1 >> 2, ac1 = (c1 & 3) * 8;

  f32x4 acc[4][4] = {};

  for (int kt = 0; kt < K; kt += 32) {
    gl2lds16(A + (size_t)(m0 + ar0) * K + kt + ac0, (void*)(As + wave * 512));
    gl2lds16(A + (size_t)(m0 + ar1) * K + kt + ac1, (void*)(As + 2048 + wave * 512));
    gl2lds16(B + (size_t)(n0 + ar0) * K + kt + ac0, (void*)(Bs + wave * 512));
    gl2lds16(B + (size_t)(n0 + ar1) * K + kt + ac1, (void*)(Bs + 2048 + wave * 512));
    asm volatile("s_waitcnt vmcnt(0)" ::: "memory");
    __syncthreads();
    bf16x8 a[4], b[4];
    #pragma unroll
    for (int i = 0; i < 4; i++) a[i] = *(const bf16x8*)(As + (wr + i * 16 + r) * 32 + ko);
    #pragma unroll
    for (int i = 0; i < 4; i++) b[i] = *(const bf16x8*)(Bs + (wc + i * 16 + r) * 32 + ko);
    #pragma unroll
    for (int i = 0; i < 4; i++)
      #pragma unroll
      for (int j = 0; j < 4; j++)
        acc[i][j] = __builtin_amdgcn_mfma_f32_16x16x32_bf16(a[i], b[j], acc[i][j], 0, 0, 0);
    __syncthreads();
  }

  #pragma unroll
  for (int i = 0; i < 4; i++)
    #pragma unroll
    for (int j = 0; j < 4; j++)
      #pragma unroll
      for (int jj = 0; jj < 4; jj++) {
        const int gr = m0 + wr + i * 16 + (lane >> 4) * 4 + jj;
        const int gc = n0 + wc + j * 16 + r;
        const size_t off = (size_t)gr * N + gc;
        const float v = acc[i][j][jj];
        if (MODE == 0) {
          ((bf16_t*)out0)[off] = (bf16_t)(1.0f / (1.0f + expf(-v)));
        } else if (MODE == 1) {
          ((bf16_t*)out0)[off] = (bf16_t)(1.0f / (1.0f + expf(v)));
          out1[off] = fminf(v, 0.0f) - log1pf(expf(-fabsf(v)));
        } else if (MODE == 2) {
          ((bf16_t*)out0)[off] = (bf16_t)v;
        } else {
          ((float*)out0)[off] = v;
        }
      }
}

// ---------------------------------------------------------------------------
__global__ void f2b_kernel(const float* __restrict__ in, bf16_t* __restrict__ out, int n8)
{
  const int idx = blockIdx.x * 256 + threadIdx.x;
  if (idx >= n8) return;
  const float4 a = *(const float4*)(in + (size_t)idx * 8);
  const float4 b = *(const float4*)(in + (size_t)idx * 8 + 4);
  bf16x8 o;
  o[0] = (bf16_t)a.x; o[1] = (bf16_t)a.y; o[2] = (bf16_t)a.z; o[3] = (bf16_t)a.w;
  o[4] = (bf16_t)b.x; o[5] = (bf16_t)b.y; o[6] = (bf16_t)b.z; o[7] = (bf16_t)b.w;
  *(bf16x8*)(out + (size_t)idx * 8) = o;
}

// ---------------------------------------------------------------------------
// prep2: per (b,h,c): gc = cumsum(g); IN-PLACE q <- q*e^(gc-gl/2),
// k <- k*e^(gl/2-gc); eglh[blk][d] = e^(gl_d/2).  (mid-point gauge: both
// stored tensors span only e^+-43 -> no bf16 subnormal flush / overflow)
// ---------------------------------------------------------------------------
__global__ __launch_bounds__(256)
void prep2_kernel(bf16_t* __restrict__ qb, bf16_t* __restrict__ kb,
                  const float* __restrict__ g32, float* __restrict__ eglh)
{
  __shared__ __align__(16) float gs[64][132];
  __shared__ float gls[128];
  const int blk = blockIdx.x;
  const int c = blk & 31, h = (blk >> 5) & 15, b = blk >> 9;
  const size_t row0 = (size_t)b * 2048 + (size_t)c * 64;
  const int col0 = h * 128;
  const int tt = threadIdx.x;

  #pragma unroll
  for (int s = 0; s < 8; s++) {
    const int u = tt + s * 256;
    const int t = u >> 5, d4 = (u & 31) * 4;
    *(float4*)&gs[t][d4] = *(const float4*)(g32 + (row0 + t) * 2048 + col0 + d4);
  }
  __syncthreads();
  if (tt < 128) {
    float run = 0.0f;
    for (int t = 0; t < 64; t++) { run += gs[t][tt]; gs[t][tt] = run; }
    gls[tt] = 0.5f * run;
    eglh[(size_t)blk * 128 + tt] = expf(0.5f * run);
  }
  __syncthreads();
  #pragma unroll
  for (int s = 0; s < 4; s++) {
    const int u = tt + s * 256;
    const int t = u >> 4, d8 = (u & 15) * 8;
    bf16_t* qp = qb + (row0 + t) * 2048 + col0 + d8;
    bf16_t* kp = kb + (row0 + t) * 2048 + col0 + d8;
    const bf16x8 q8 = *(const bf16x8*)qp;
    const bf16x8 k8 = *(const bf16x8*)kp;
    bf16x8 qo, ko2;
    #pragma unroll
    for (int j = 0; j < 8; j++) {
      const float gc = gs[t][d8 + j];
      const float gh = gls[d8 + j];
      qo[j]  = (bf16_t)((float)q8[j] * expf(gc - gh));
      ko2[j] = (bf16_t)((float)k8[j] * expf(gh - gc));
    }
    *(bf16x8*)qp = qo;
    *(bf16x8*)kp = ko2;
  }
}

// ---------------------------------------------------------------------------
// state2: per (bh, e-half, d-half): sequential 32-chunk recurrence on a
// 64x64 quarter of T = S^T. kg = kd2 * e^(gl/2). Stores pre-update state
// scaled by e^(gl_c/2): ST'[cb][e][d].
// ---------------------------------------------------------------------------
__global__ __launch_bounds__(256)
void state2_kernel(const bf16_t* __restrict__ kb, const bf16_t* __restrict__ vb,
                   const float* __restrict__ eglh, bf16_t* __restrict__ ST)
{
  __shared__ __align__(16) bf16_t kgt[64][72];
  __shared__ __align__(16) bf16_t vt[64][72];
  __shared__ float ehs[64];
  const int blk = blockIdx.x;                   // bh*4 + eh*2 + dh
  const int dh = blk & 1, eh = (blk >> 1) & 1, bh = blk >> 2;
  const int b = bh >> 4, h = bh & 15;
  const int col0 = h * 128;
  const int tt = threadIdx.x, wave = tt >> 6, lane = tt & 63;
  const int r = lane & 15, ko = (lane >> 4) * 8;
  const int d0 = dh * 64, e0 = eh * 64;
  f32x4 acc[4] = {};

  for (int c = 0; c < 32; c++) {
    const size_t cb = (size_t)bh * 32 + c;
    const size_t row0 = (size_t)b * 2048 + (size_t)c * 64;
    if (tt < 64) ehs[tt] = eglh[cb * 128 + d0 + tt];
    __syncthreads();
    #pragma unroll
    for (int s = 0; s < 2; s++) {
      const int u = tt + s * 256;
      const int t = u >> 3, d8 = (u & 7) * 8;
      const bf16x8 kv = *(const bf16x8*)(kb + (row0 + t) * 2048 + col0 + d0 + d8);
      const bf16x8 vv = *(const bf16x8*)(vb + (row0 + t) * 2048 + col0 + e0 + d8);
      #pragma unroll
      for (int j = 0; j < 8; j++) {
        kgt[d8 + j][t] = (bf16_t)((float)kv[j] * ehs[d8 + j]);
        vt[d8 + j][t]  = vv[j];
      }
    }
    __syncthreads();
    #pragma unroll
    for (int nf = 0; nf < 4; nf++) {
      const int d = nf * 16 + r;
      const float sd = ehs[d];
      #pragma unroll
      for (int jj = 0; jj < 4; jj++) {
        const int e = e0 + wave * 16 + (lane >> 4) * 4 + jj;
        ST[(cb * 128 + e) * 128 + d0 + d] = (bf16_t)(acc[nf][jj] * sd);
      }
    }
    #pragma unroll
    for (int nf = 0; nf < 4; nf++) {
      const float ev = ehs[nf * 16 + r];
      const float e2 = ev * ev;
      #pragma unroll
      for (int jj = 0; jj < 4; jj++) acc[nf][jj] *= e2;
    }
    #pragma unroll
    for (int ks = 0; ks < 2; ks++) {
      const bf16x8 a = *(const bf16x8*)&vt[wave * 16 + r][ks * 32 + ko];
      #pragma unroll
      for (int nf = 0; nf < 4; nf++) {
        const bf16x8 bfr = *(const bf16x8*)&kgt[nf * 16 + r][ks * 32 + ko];
        acc[nf] = __builtin_amdgcn_mfma_f32_16x16x32_bf16(a, bfr, acc[nf], 0, 0, 0);
      }
    }
    __syncthreads();
  }
}

// ---------------------------------------------------------------------------
// chunk2: per (b,h,c): A = qg2 @ kd2^T (tril) -> P ; o = P@v + qg2@ST'
// ---------------------------------------------------------------------------
__global__ __launch_bounds__(256)
void chunk2_kernel(const bf16_t* __restrict__ qb, const bf16_t* __restrict__ kb,
                   const bf16_t* __restrict__ vb, const bf16_t* __restrict__ ST,
                   bf16_t* __restrict__ o16)
{
  __shared__ __align__(16) bf16_t qgs[64][136];
  __shared__ __align__(16) bf16_t kds[64][136];
  __shared__ __align__(16) bf16_t vTs[128][72];
  __shared__ __align__(16) bf16_t Ps[64][72];
  const int blk = blockIdx.x;
  const int c = blk & 31, h = (blk >> 5) & 15, b = blk >> 9;
  const size_t row0 = (size_t)b * 2048 + (size_t)c * 64;
  const int col0 = h * 128;
  const int tt = threadIdx.x, wave = tt >> 6, lane = tt & 63;
  const int r = lane & 15, ko = (lane >> 4) * 8;

  #pragma unroll
  for (int s = 0; s < 4; s++) {
    const int u = tt + s * 256;
    const int t = u >> 4, d8 = (u & 15) * 8;
    *(bf16x8*)&qgs[t][d8] = *(const bf16x8*)(qb + (row0 + t) * 2048 + col0 + d8);
    *(bf16x8*)&kds[t][d8] = *(const bf16x8*)(kb + (row0 + t) * 2048 + col0 + d8);
  }
  #pragma unroll
  for (int s = 0; s < 4; s++) {
    const int u = tt + s * 256;
    const int t = u >> 4, e8 = (u & 15) * 8;
    const bf16x8 vv = *(const bf16x8*)(vb + (row0 + t) * 2048 + col0 + e8);
    #pragma unroll
    for (int j = 0; j < 8; j++) vTs[e8 + j][t] = vv[j];
  }
  __syncthreads();

  bf16x8 aq[4];
  #pragma unroll
  for (int ks = 0; ks < 4; ks++) aq[ks] = *(const bf16x8*)&qgs[wave * 16 + r][ks * 32 + ko];

  f32x4 accA[4] = {};
  #pragma unroll
  for (int ks = 0; ks < 4; ks++)
    #pragma unroll
    for (int sf = 0; sf < 4; sf++) {
      const bf16x8 bfr = *(const bf16x8*)&kds[sf * 16 + r][ks * 32 + ko];
      accA[sf] = __builtin_amdgcn_mfma_f32_16x16x32_bf16(aq[ks], bfr, accA[sf], 0, 0, 0);
    }

  #pragma unroll
  for (int sf = 0; sf < 4; sf++)
    #pragma unroll
    for (int jj = 0; jj < 4; jj++) {
      const int t = wave * 16 + (lane >> 4) * 4 + jj;
      const int s = sf * 16 + r;
      Ps[t][s] = (bf16_t)(t >= s ? accA[sf][jj] : 0.0f);
    }

  f32x4 acc[8] = {};
  const size_t stbase = (size_t)blk * 128 * 128;
  #pragma unroll
  for (int ks = 0; ks < 4; ks++)
    #pragma unroll
    for (int ne = 0; ne < 8; ne++) {
      const bf16x8 bfr = *(const bf16x8*)(ST + stbase + (size_t)(ne * 16 + r) * 128 + ks * 32 + ko);
      acc[ne] = __builtin_amdgcn_mfma_f32_16x16x32_bf16(aq[ks], bfr, acc[ne], 0, 0, 0);
    }
  #pragma unroll
  for (int ks = 0; ks < 2; ks++) {
    const bf16x8 pa = *(const bf16x8*)&Ps[wave * 16 + r][ks * 32 + ko];
    #pragma unroll
    for (int ne = 0; ne < 8; ne++) {
      const bf16x8 bfr = *(const bf16x8*)&vTs[ne * 16 + r][ks * 32 + ko];
      acc[ne] = __builtin_amdgcn_mfma_f32_16x16x32_bf16(pa, bfr, acc[ne], 0, 0, 0);
    }
  }

  #pragma unroll
  for (int ne = 0; ne < 8; ne++)
    #pragma unroll
    for (int jj = 0; jj < 4; jj++) {
      const int t = wave * 16 + (lane >> 4) * 4 + jj;
      const int e = ne * 16 + r;
      o16[(row0 + t) * 2048 + col0 + e] = (bf16_t)acc[ne][jj];
    }
}

// ---------------------------------------------------------------------------
// RMSNorm over D=2048, bf16 in -> bf16 out
// ---------------------------------------------------------------------------
__global__ __launch_bounds__(256)
void rmsb_kernel(const bf16_t* __restrict__ o16, const float* __restrict__ w,
                 bf16_t* __restrict__ ob)
{
  __shared__ float red[4];
  const size_t row = blockIdx.x;
  const int tt = threadIdx.x;
  const bf16x8 v = *(const bf16x8*)(o16 + row * 2048 + tt * 8);
  float f[8], ss = 0.0f;
  #pragma unroll
  for (int j = 0; j < 8; j++) { f[j] = (float)v[j]; ss += f[j] * f[j]; }
  #pragma unroll
  for (int off = 32; off > 0; off >>= 1) ss += __shfl_down(ss, off);
  if ((tt & 63) == 0) red[tt >> 6] = ss;
  __syncthreads();
  const float inv = rsqrtf((red[0] + red[1] + red[2] + red[3]) * (1.0f / 2048.0f) + 1e-5f);
  const float4 w0 = *(const float4*)(w + tt * 8);
  const float4 w1 = *(const float4*)(w + tt * 8 + 4);
  bf16x8 o;
  o[0] = (bf16_t)(f[0] * inv * w0.x); o[1] = (bf16_t)(f[1] * inv * w0.y);
  o[2] = (bf16_t)(f[2] * inv * w0.z); o[3] = (bf16_t)(f[3] * inv * w0.w);
  o[4] = (bf16_t)(f[4] * inv * w1.x); o[5] = (bf16_t)(f[5] * inv * w1.y);
  o[6] = (bf16_t)(f[6] * inv * w1.z); o[7] = (bf16_t)(f[7] * inv * w1.w);
  *(bf16x8*)(ob + row * 2048 + tt * 8) = o;
}

// ---------------------------------------------------------------------------
extern "C" void kernel_launch(void* const* d_in, const int* in_sizes, int n_in,
                              void* d_out, int out_size, void* d_ws, size_t ws_size,
                              hipStream_t stream)
{
  const float* x  = (const float*)d_in[0];
  const float* Wq = (const float*)d_in[1];
  const float* Wf = (const float*)d_in[2];
  const float* Wi = (const float*)d_in[3];
  const float* Wo = (const float*)d_in[4];
  const float* gw = (const float*)d_in[5];
  float* out = (float*)d_out;
  char* ws = (char*)d_ws;

  const int N = 2048, K = 2048;
  const size_t MB = 1ull << 20;

  auto run = [&](const float* xs, float* outs, int nbs) {
    const int Ms = nbs * 2048;
    const size_t Sx = (size_t)Ms * 2048 * 2;     // bf16 matrix bytes
    bf16_t* xb  = (bf16_t*)(ws + 0);
    bf16_t* qb  = (bf16_t*)(ws + Sx);
    bf16_t* kb  = (bf16_t*)(ws + 2 * Sx);
    bf16_t* vb  = (bf16_t*)(ws + 3 * Sx);
    float*  g32 = (float*) (ws + 4 * Sx);        // 2*Sx bytes
    bf16_t* Wb  = (bf16_t*)(ws + 6 * Sx);        // 8 MiB
    float*  egh = (float*) (ws + 6 * Sx + 8 * MB);
    bf16_t* STp = (bf16_t*)(ws + 4 * Sx);        // alias g32 (dead after prep)
    bf16_t* o16 = (bf16_t*)(ws + 0);             // alias xb  (dead after gemm<2>)
    bf16_t* ob  = (bf16_t*)(ws + Sx);            // alias qb  (dead after chunk)

    const int n8x = Ms * 2048 / 8;
    const int n8w = N * K / 8;
    const int gemmGrid = (Ms / 128) * (N / 128);

    f2b_kernel<<<(n8x + 255) / 256, 256, 0, stream>>>(xs, xb, n8x);

    f2b_kernel<<<(n8w + 255) / 256, 256, 0, stream>>>(Wq, Wb, n8w);
    gemm_bt<0><<<gemmGrid, 256, 0, stream>>>(xb, Wb, qb, nullptr, Ms, N, K);

    f2b_kernel<<<(n8w + 255) / 256, 256, 0, stream>>>(Wf, Wb, n8w);
    gemm_bt<1><<<gemmGrid, 256, 0, stream>>>(xb, Wb, kb, g32, Ms, N, K);

    f2b_kernel<<<(n8w + 255) / 256, 256, 0, stream>>>(Wi, Wb, n8w);
    gemm_bt<2><<<gemmGrid, 256, 0, stream>>>(xb, Wb, vb, nullptr, Ms, N, K);

    prep2_kernel<<<nbs * 512, 256, 0, stream>>>(qb, kb, g32, egh);
    state2_kernel<<<nbs * 64, 256, 0, stream>>>(kb, vb, egh, STp);
    chunk2_kernel<<<nbs * 512, 256, 0, stream>>>(qb, kb, vb, STp, o16);
    rmsb_kernel<<<Ms, 256, 0, stream>>>(o16, gw, ob);

    f2b_kernel<<<(n8w + 255) / 256, 256, 0, stream>>>(Wo, Wb, n8w);
    gemm_bt<3><<<gemmGrid, 256, 0, stream>>>(ob, Wb, outs, nullptr, Ms, N, K);
  };

  const size_t Sx_full = (size_t)8192 * 2048 * 2;
  const size_t need_full = 6 * Sx_full + 8 * MB + 4 * 512 * 128 * 4;
  if (ws_size >= need_full) {
    run(x, out, 4);
  } else {
    for (int sb = 0; sb < 4; sb++)
      run(x + (size_t)sb * 2048 * 2048, out + (size_t)sb * 2048 * 2048, 1);
  }

  (void)in_sizes; (void)n_in; (void)out_size;
}